// Round 7
// baseline (112.274 us; speedup 1.0000x reference)
//
#include <hip/hip_runtime.h>
#include <hip/hip_bf16.h>

typedef unsigned short u16;
typedef unsigned int u32;
typedef unsigned char u8;
typedef int i32x8 __attribute__((ext_vector_type(8)));
typedef float f32x4 __attribute__((ext_vector_type(4)));

#define NSPK 1024
#define NUTT 20
#define DEMB 512
#define NROW (NSPK * NUTT)   // 20480

// pack 8 fp32 -> 8 fp8 e4m3 bytes (HW cvt, gfx950 OCP format — same format MFMA eats)
__device__ __forceinline__ uint2 pk_fp8x8(float a, float b, float c, float d,
                                          float e, float f, float g, float h) {
    int lo = __builtin_amdgcn_cvt_pk_fp8_f32(a, b, 0, 0);
    lo = __builtin_amdgcn_cvt_pk_fp8_f32(c, d, lo, 1);
    int hi = __builtin_amdgcn_cvt_pk_fp8_f32(e, f, 0, 0);
    hi = __builtin_amdgcn_cvt_pk_fp8_f32(g, h, hi, 1);
    return make_uint2((u32)lo, (u32)hi);
}

// ---------------------------------------------------------------------------
// Fused prep (R6-validated, byte-identical): one block per speaker; wave wv
// owns rows 5wv..5wv+4, lane owns dims 8l..8l+7. Reads E once, one barrier.
// Emits FP8 e_n rows (A), FP8 c_n (Bc), fp32 diag/csd; zeroes rowsum and out.
// ---------------------------------------------------------------------------
__global__ __launch_bounds__(256) void prep_f(const float* __restrict__ E,
                                              u8* __restrict__ A,
                                              u8* __restrict__ Bc,
                                              float* __restrict__ diag,
                                              float* __restrict__ csd,
                                              float* __restrict__ rs,
                                              float* __restrict__ out) {
    __shared__ float sbuf[4][DEMB];
    const int t = threadIdx.x, lane = t & 63, wv = t >> 6;
    const int n = blockIdx.x;
    const float* Eb = E + (size_t)n * (NUTT * DEMB) + (size_t)(wv * 5) * DEMB + lane * 8;

    float4 e0[5], e1[5];
    float4 p0 = {0, 0, 0, 0}, p1 = {0, 0, 0, 0};
#pragma unroll
    for (int i = 0; i < 5; ++i) {
        e0[i] = *(const float4*)(Eb + (size_t)i * DEMB);
        e1[i] = *(const float4*)(Eb + (size_t)i * DEMB + 4);
        p0.x += e0[i].x; p0.y += e0[i].y; p0.z += e0[i].z; p0.w += e0[i].w;
        p1.x += e1[i].x; p1.y += e1[i].y; p1.z += e1[i].z; p1.w += e1[i].w;
    }
    *(float4*)(&sbuf[wv][lane * 8])     = p0;
    *(float4*)(&sbuf[wv][lane * 8 + 4]) = p1;
    __syncthreads();

    float4 s0 = {0, 0, 0, 0}, s1 = {0, 0, 0, 0};
#pragma unroll
    for (int k = 0; k < 4; ++k) {
        float4 a = *(const float4*)(&sbuf[k][lane * 8]);
        float4 b = *(const float4*)(&sbuf[k][lane * 8 + 4]);
        s0.x += a.x; s0.y += a.y; s0.z += a.z; s0.w += a.w;
        s1.x += b.x; s1.y += b.y; s1.z += b.z; s1.w += b.w;
    }

    float ls = s0.x*s0.x + s0.y*s0.y + s0.z*s0.z + s0.w*s0.w
             + s1.x*s1.x + s1.y*s1.y + s1.z*s1.z + s1.w*s1.w;
#pragma unroll
    for (int o = 32; o; o >>= 1) ls += __shfl_xor(ls, o);
    const float ss = ls;                                       // ||s||^2
    const float rc = 1.0f / fmaxf(sqrtf(ss) * 0.05f, 1e-8f);   // 1/max(||c||,eps)
    const float g  = rc * 0.05f;                               // rc/20

    ((uint2*)(Bc + (size_t)n * DEMB))[lane] =
        pk_fp8x8(s0.x * g, s0.y * g, s0.z * g, s0.w * g,
                 s1.x * g, s1.y * g, s1.z * g, s1.w * g);

#pragma unroll
    for (int i = 0; i < 5; ++i) {
        float ee = e0[i].x*e0[i].x + e0[i].y*e0[i].y + e0[i].z*e0[i].z + e0[i].w*e0[i].w
                 + e1[i].x*e1[i].x + e1[i].y*e1[i].y + e1[i].z*e1[i].z + e1[i].w*e1[i].w;
        float es = e0[i].x*s0.x + e0[i].y*s0.y + e0[i].z*s0.z + e0[i].w*s0.w
                 + e1[i].x*s1.x + e1[i].y*s1.y + e1[i].z*s1.z + e1[i].w*s1.w;
#pragma unroll
        for (int o = 32; o; o >>= 1) { ee += __shfl_xor(ee, o); es += __shfl_xor(es, o); }

        const float rne = 1.0f / fmaxf(sqrtf(ee), 1e-8f);
        const float pxx = ss - 2.f * es + ee;                  // ||s-e||^2
        const float dg  = (es - ee) * rne / fmaxf(sqrtf(pxx), 1.9e-7f);

        const int r = n * NUTT + wv * 5 + i;
        ((uint2*)(A + (size_t)r * DEMB))[lane] =
            pk_fp8x8(e0[i].x * rne, e0[i].y * rne, e0[i].z * rne, e0[i].w * rne,
                     e1[i].x * rne, e1[i].y * rne, e1[i].z * rne, e1[i].w * rne);
        if (lane == 0) {
            diag[r] = dg;
            csd[r]  = es * g * rne;
        }
    }

    if (t < NUTT) rs[n * NUTT + t] = 0.f;
    if (n == 0 && t == 0) out[0] = 0.f;
}

// ---------------------------------------------------------------------------
// MX-FP8 GEMM [20480x512] x [1024x512]^T, fused exp row-sum epilogue.
// 128M x 256N tile, 512 threads (8 waves, 2x4 of 64x64), BK=128 (4 k-iters
// of 16x16x128 f8f6f4, unit scales). grid (160,4): A staged 4x (was 8x in
// R6), total L2 staging 123 MB (was 168). Linear id = x+160y, 160%8==0 ->
// all 4 N-blocks of an M-tile land on the SAME XCD -> A-tile L2 reuse.
// Tile arithmetic correctness-validated in R5 (absmax 0.0); epilogue is the
// fence-free atomicAdd form (R4/R6). NO __threadfence anywhere (R5 lesson:
// per-block device fence = L2 writeback walk = ~85 us stall).
// ---------------------------------------------------------------------------
__device__ __forceinline__ void async_copy16(const void* g, void* l) {
    __builtin_amdgcn_global_load_lds(
        (const __attribute__((address_space(1))) void*)g,
        (__attribute__((address_space(3))) void*)l, 16, 0, 0);
}

__global__ __launch_bounds__(512) void gemm_mx(const u8* __restrict__ A,
                                               const u8* __restrict__ Bc,
                                               const float* __restrict__ wp,
                                               const float* __restrict__ bp,
                                               float* __restrict__ rowsum) {
    __shared__ u8 As[128 * 128];   // 16 KB
    __shared__ u8 Bs[256 * 128];   // 32 KB
    const int t = threadIdx.x;
    const int lane = t & 63, wv = t >> 6;
    const int ml = lane & 15, q = lane >> 4;
    const int wm = wv >> 2, wn = wv & 3;        // 2 x 4 wave grid
    const int tileM = blockIdx.x;               // 0..159
    const int tileN = blockIdx.y;               // 0..3

    const float w = *wp, bb = *bp;

    const u8* Ag = A + (size_t)tileM * 128 * DEMB;
    const u8* Bg = Bc + (size_t)tileN * 256 * DEMB;

    // staging: chunk c -> row r=c>>3, dest slot c&7 (dest linear in c, so
    // per-wave dest = uniform base + lane*16), source k-group (c&7)^(r&7).
    // XOR k-permutation applied identically to A and B cancels in the dot.
    const u8* asrc[2]; u8* adst[2];
#pragma unroll
    for (int j = 0; j < 2; ++j) {
        const int c = t + 512 * j;              // 0..1023 (128 rows)
        const int r = c >> 3, kg = (c & 7) ^ (r & 7);
        asrc[j] = Ag + (size_t)r * DEMB + kg * 16;  adst[j] = As + c * 16;
    }
    const u8* bsrc[4]; u8* bdst[4];
#pragma unroll
    for (int j = 0; j < 4; ++j) {
        const int c = t + 512 * j;              // 0..2047 (256 rows)
        const int r = c >> 3, kg = (c & 7) ^ (r & 7);
        bsrc[j] = Bg + (size_t)r * DEMB + kg * 16;  bdst[j] = Bs + c * 16;
    }

    // fragment read offsets: quad q covers logical chunks 2q,2q+1 of row r.
    int a0[4], a1[4], b0[4], b1[4];
#pragma unroll
    for (int i = 0; i < 4; ++i) {
        const int r = wm * 64 + i * 16 + ml;
        const int c = wn * 64 + i * 16 + ml;
        a0[i] = r * 128 + (((2 * q)     ^ (r & 7)) << 4);
        a1[i] = r * 128 + (((2 * q + 1) ^ (r & 7)) << 4);
        b0[i] = c * 128 + (((2 * q)     ^ (c & 7)) << 4);
        b1[i] = c * 128 + (((2 * q + 1) ^ (c & 7)) << 4);
    }

    f32x4 acc[4][4];
#pragma unroll
    for (int i = 0; i < 4; ++i)
#pragma unroll
        for (int j = 0; j < 4; ++j) acc[i][j] = (f32x4){0.f, 0.f, 0.f, 0.f};

    for (int kt = 0; kt < DEMB; kt += 128) {
        __syncthreads();
#pragma unroll
        for (int j = 0; j < 2; ++j) async_copy16(asrc[j] + kt, adst[j]);
#pragma unroll
        for (int j = 0; j < 4; ++j) async_copy16(bsrc[j] + kt, bdst[j]);
        __syncthreads();

        i32x8 af[4], bf[4];
#pragma unroll
        for (int i = 0; i < 4; ++i) {
            uint4 x = *(const uint4*)(As + a0[i]);
            uint4 y = *(const uint4*)(As + a1[i]);
            af[i] = (i32x8){(int)x.x, (int)x.y, (int)x.z, (int)x.w,
                            (int)y.x, (int)y.y, (int)y.z, (int)y.w};
        }
#pragma unroll
        for (int j = 0; j < 4; ++j) {
            uint4 x = *(const uint4*)(Bs + b0[j]);
            uint4 y = *(const uint4*)(Bs + b1[j]);
            bf[j] = (i32x8){(int)x.x, (int)x.y, (int)x.z, (int)x.w,
                            (int)y.x, (int)y.y, (int)y.z, (int)y.w};
        }
#pragma unroll
        for (int i = 0; i < 4; ++i)
#pragma unroll
            for (int j = 0; j < 4; ++j)
                acc[i][j] = __builtin_amdgcn_mfma_scale_f32_16x16x128_f8f6f4(
                    af[i], bf[j], acc[i][j], 0, 0,
                    0, 0x7F7F7F7F, 0, 0x7F7F7F7F);   // unit scales (E8M0 127)
    }

    // epilogue: exp + row-sum. C/D layout: col = lane&15, row = q*4 + reg.
#pragma unroll
    for (int i = 0; i < 4; ++i) {
        float s0 = 0.f, s1 = 0.f, s2 = 0.f, s3 = 0.f;
#pragma unroll
        for (int j = 0; j < 4; ++j) {
            s0 += __expf(fmaf(w, acc[i][j][0] + 1e-6f, bb));
            s1 += __expf(fmaf(w, acc[i][j][1] + 1e-6f, bb));
            s2 += __expf(fmaf(w, acc[i][j][2] + 1e-6f, bb));
            s3 += __expf(fmaf(w, acc[i][j][3] + 1e-6f, bb));
        }
#pragma unroll
        for (int o = 1; o < 16; o <<= 1) {
            s0 += __shfl_xor(s0, o); s1 += __shfl_xor(s1, o);
            s2 += __shfl_xor(s2, o); s3 += __shfl_xor(s3, o);
        }
        if (ml < 4) {
            float sv = (ml == 0) ? s0 : (ml == 1) ? s1 : (ml == 2) ? s2 : s3;
            int grow = tileM * 128 + wm * 64 + i * 16 + q * 4 + ml;
            atomicAdd(&rowsum[grow], sv);
        }
    }
}

// ---------------------------------------------------------------------------
// Finalize (R6-validated, byte-identical): per-row diagonal fixup + log +
// reduction. Separate dispatch = cheap device-wide visibility of rowsum.
// ---------------------------------------------------------------------------
__global__ __launch_bounds__(256) void finalize(const float* __restrict__ rowsum,
                                                const float* __restrict__ diag,
                                                const float* __restrict__ csd,
                                                const float* __restrict__ wp,
                                                const float* __restrict__ bp,
                                                float* __restrict__ out) {
    __shared__ float s_red[4];
    const int r = blockIdx.x * 256 + threadIdx.x;   // 80*256 == 20480 exactly
    const float w = *wp, bb = *bp;
    const float dg = diag[r];
    const float pos = fmaf(w, dg + 1e-6f, bb);
    const float S = rowsum[r] - __expf(fmaf(w, csd[r] + 1e-6f, bb)) + __expf(pos);
    float term = __logf(S + 1e-6f) - pos;
    const int lane = threadIdx.x & 63, wv = threadIdx.x >> 6;
#pragma unroll
    for (int o = 32; o; o >>= 1) term += __shfl_xor(term, o);
    if (lane == 0) s_red[wv] = term;
    __syncthreads();
    if (threadIdx.x == 0) atomicAdd(out, s_red[0] + s_red[1] + s_red[2] + s_red[3]);
}

extern "C" void kernel_launch(void* const* d_in, const int* in_sizes, int n_in,
                              void* d_out, int out_size, void* d_ws, size_t ws_size,
                              hipStream_t stream) {
    const float* E = (const float*)d_in[0];
    const float* wp = (const float*)d_in[1];
    const float* bp = (const float*)d_in[2];
    float* out = (float*)d_out;

    char* ws = (char*)d_ws;
    u8* A      = (u8*)(ws);                        // 20480*512   = 10,485,760 B
    u8* Bc     = (u8*)(ws + 10485760);             //  1024*512   =     524,288 B
    float* dg  = (float*)(ws + 11010048);          // 20480*4
    float* cs  = (float*)(ws + 11091968);          // 20480*4
    float* rs  = (float*)(ws + 11173888);          // 20480*4

    prep_f<<<NSPK, 256, 0, stream>>>(E, A, Bc, dg, cs, rs, out);
    gemm_mx<<<dim3(160, 4), 512, 0, stream>>>(A, Bc, wp, bp, rs);
    finalize<<<80, 256, 0, stream>>>(rs, dg, cs, wp, bp, out);
}

// Round 8
// 108.118 us; speedup vs baseline: 1.0384x; 1.0384x over previous
//
#include <hip/hip_runtime.h>
#include <hip/hip_bf16.h>

typedef unsigned short u16;
typedef unsigned int u32;
typedef unsigned char u8;
typedef int i32x8 __attribute__((ext_vector_type(8)));
typedef float f32x4 __attribute__((ext_vector_type(4)));

#define NSPK 1024
#define NUTT 20
#define DEMB 512
#define NROW (NSPK * NUTT)   // 20480

// pack 8 fp32 -> 8 fp8 e4m3 bytes (HW cvt, gfx950 OCP format — same format MFMA eats)
__device__ __forceinline__ uint2 pk_fp8x8(float a, float b, float c, float d,
                                          float e, float f, float g, float h) {
    int lo = __builtin_amdgcn_cvt_pk_fp8_f32(a, b, 0, 0);
    lo = __builtin_amdgcn_cvt_pk_fp8_f32(c, d, lo, 1);
    int hi = __builtin_amdgcn_cvt_pk_fp8_f32(e, f, 0, 0);
    hi = __builtin_amdgcn_cvt_pk_fp8_f32(g, h, hi, 1);
    return make_uint2((u32)lo, (u32)hi);
}

// ---------------------------------------------------------------------------
// Fused prep (R6-validated): one block per speaker; wave wv owns rows
// 5wv..5wv+4, lane owns dims 8l..8l+7. Reads E once, one barrier. Emits FP8
// e_n rows (A), FP8 c_n (Bc), fp32 diag/csd; zeroes rowsum and out.
// ---------------------------------------------------------------------------
__global__ __launch_bounds__(256) void prep_f(const float* __restrict__ E,
                                              u8* __restrict__ A,
                                              u8* __restrict__ Bc,
                                              float* __restrict__ diag,
                                              float* __restrict__ csd,
                                              float* __restrict__ rs,
                                              float* __restrict__ out) {
    __shared__ float sbuf[4][DEMB];
    const int t = threadIdx.x, lane = t & 63, wv = t >> 6;
    const int n = blockIdx.x;
    const float* Eb = E + (size_t)n * (NUTT * DEMB) + (size_t)(wv * 5) * DEMB + lane * 8;

    float4 e0[5], e1[5];
    float4 p0 = {0, 0, 0, 0}, p1 = {0, 0, 0, 0};
#pragma unroll
    for (int i = 0; i < 5; ++i) {
        e0[i] = *(const float4*)(Eb + (size_t)i * DEMB);
        e1[i] = *(const float4*)(Eb + (size_t)i * DEMB + 4);
        p0.x += e0[i].x; p0.y += e0[i].y; p0.z += e0[i].z; p0.w += e0[i].w;
        p1.x += e1[i].x; p1.y += e1[i].y; p1.z += e1[i].z; p1.w += e1[i].w;
    }
    *(float4*)(&sbuf[wv][lane * 8])     = p0;
    *(float4*)(&sbuf[wv][lane * 8 + 4]) = p1;
    __syncthreads();

    float4 s0 = {0, 0, 0, 0}, s1 = {0, 0, 0, 0};
#pragma unroll
    for (int k = 0; k < 4; ++k) {
        float4 a = *(const float4*)(&sbuf[k][lane * 8]);
        float4 b = *(const float4*)(&sbuf[k][lane * 8 + 4]);
        s0.x += a.x; s0.y += a.y; s0.z += a.z; s0.w += a.w;
        s1.x += b.x; s1.y += b.y; s1.z += b.z; s1.w += b.w;
    }

    float ls = s0.x*s0.x + s0.y*s0.y + s0.z*s0.z + s0.w*s0.w
             + s1.x*s1.x + s1.y*s1.y + s1.z*s1.z + s1.w*s1.w;
#pragma unroll
    for (int o = 32; o; o >>= 1) ls += __shfl_xor(ls, o);
    const float ss = ls;                                       // ||s||^2
    const float rc = 1.0f / fmaxf(sqrtf(ss) * 0.05f, 1e-8f);   // 1/max(||c||,eps)
    const float g  = rc * 0.05f;                               // rc/20

    ((uint2*)(Bc + (size_t)n * DEMB))[lane] =
        pk_fp8x8(s0.x * g, s0.y * g, s0.z * g, s0.w * g,
                 s1.x * g, s1.y * g, s1.z * g, s1.w * g);

#pragma unroll
    for (int i = 0; i < 5; ++i) {
        float ee = e0[i].x*e0[i].x + e0[i].y*e0[i].y + e0[i].z*e0[i].z + e0[i].w*e0[i].w
                 + e1[i].x*e1[i].x + e1[i].y*e1[i].y + e1[i].z*e1[i].z + e1[i].w*e1[i].w;
        float es = e0[i].x*s0.x + e0[i].y*s0.y + e0[i].z*s0.z + e0[i].w*s0.w
                 + e1[i].x*s1.x + e1[i].y*s1.y + e1[i].z*s1.z + e1[i].w*s1.w;
#pragma unroll
        for (int o = 32; o; o >>= 1) { ee += __shfl_xor(ee, o); es += __shfl_xor(es, o); }

        const float rne = 1.0f / fmaxf(sqrtf(ee), 1e-8f);
        const float pxx = ss - 2.f * es + ee;                  // ||s-e||^2
        const float dg  = (es - ee) * rne / fmaxf(sqrtf(pxx), 1.9e-7f);

        const int r = n * NUTT + wv * 5 + i;
        ((uint2*)(A + (size_t)r * DEMB))[lane] =
            pk_fp8x8(e0[i].x * rne, e0[i].y * rne, e0[i].z * rne, e0[i].w * rne,
                     e1[i].x * rne, e1[i].y * rne, e1[i].z * rne, e1[i].w * rne);
        if (lane == 0) {
            diag[r] = dg;
            csd[r]  = es * g * rne;
        }
    }

    if (t < NUTT) rs[n * NUTT + t] = 0.f;
    if (n == 0 && t == 0) out[0] = 0.f;
}

// ---------------------------------------------------------------------------
// MX-FP8 GEMM [20480x512] x [1024x512]^T with fused exp row-sum epilogue.
// mfma_scale_f32_16x16x128_f8f6f4 (unit scales), 128x128 tile, BK=128 ->
// FOUR k-iterations, LDS 2x16 KB -> 5 blocks/CU, grid 1280 = exactly one
// full occupancy round (R6-validated best: 109.6 us total).
// R5 lesson: NO in-kernel __threadfence (per-block L2 writeback = ~85 us).
// R7 lesson: 128x256/grid 640 regresses (2.5-round imbalance beats the
// 45 MB L2-staging saving). 128-square at exact-round occupancy is optimal.
// ---------------------------------------------------------------------------
__device__ __forceinline__ void async_copy16(const void* g, void* l) {
    __builtin_amdgcn_global_load_lds(
        (const __attribute__((address_space(1))) void*)g,
        (__attribute__((address_space(3))) void*)l, 16, 0, 0);
}

__global__ __launch_bounds__(256) void gemm_mx(const u8* __restrict__ A,
                                               const u8* __restrict__ Bc,
                                               const float* __restrict__ wp,
                                               const float* __restrict__ bp,
                                               float* __restrict__ rowsum) {
    __shared__ u8 As[128 * 128];   // 16 KB: [row][128 k-bytes], 16B chunks swizzled
    __shared__ u8 Bs[128 * 128];   // 16 KB
    const int t = threadIdx.x;
    const int lane = t & 63, wv = t >> 6;
    const int ml = lane & 15, q = lane >> 4;
    const int wm = wv >> 1, wn = wv & 1;
    const int tileM = blockIdx.x;    // 0..159
    const int tileN = blockIdx.y;    // 0..7

    const float w = *wp, bb = *bp;

    const u8* Ag = A + (size_t)tileM * 128 * DEMB;
    const u8* Bg = Bc + (size_t)tileN * 128 * DEMB;

    // staging: chunk c = t+256j -> row r=c>>3, dest slot c&7 (dest linear in
    // lane: wave-uniform base + lane*16), source k-group (c&7)^(r&7). The
    // XOR k-permutation applied identically to A and B cancels in the dot.
    const u8* asrc[4]; const u8* bsrc[4]; u8* adst[4]; u8* bdst[4];
#pragma unroll
    for (int j = 0; j < 4; ++j) {
        const int c = t + 256 * j;
        const int r = c >> 3, kg = (c & 7) ^ (r & 7);
        asrc[j] = Ag + (size_t)r * DEMB + kg * 16;  adst[j] = As + c * 16;
        bsrc[j] = Bg + (size_t)r * DEMB + kg * 16;  bdst[j] = Bs + c * 16;
    }

    // fragment read offsets: quad q covers logical chunks 2q,2q+1 of row r.
    int a0[4], a1[4], b0[4], b1[4];
#pragma unroll
    for (int i = 0; i < 4; ++i) {
        const int r = wm * 64 + i * 16 + ml;
        const int c = wn * 64 + i * 16 + ml;
        a0[i] = r * 128 + (((2 * q)     ^ (r & 7)) << 4);
        a1[i] = r * 128 + (((2 * q + 1) ^ (r & 7)) << 4);
        b0[i] = c * 128 + (((2 * q)     ^ (c & 7)) << 4);
        b1[i] = c * 128 + (((2 * q + 1) ^ (c & 7)) << 4);
    }

    f32x4 acc[4][4];
#pragma unroll
    for (int i = 0; i < 4; ++i)
#pragma unroll
        for (int j = 0; j < 4; ++j) acc[i][j] = (f32x4){0.f, 0.f, 0.f, 0.f};

    for (int kt = 0; kt < DEMB; kt += 128) {
        __syncthreads();
#pragma unroll
        for (int j = 0; j < 4; ++j) async_copy16(asrc[j] + kt, adst[j]);
#pragma unroll
        for (int j = 0; j < 4; ++j) async_copy16(bsrc[j] + kt, bdst[j]);
        __syncthreads();

        i32x8 af[4], bf[4];
#pragma unroll
        for (int i = 0; i < 4; ++i) {
            uint4 x = *(const uint4*)(As + a0[i]);
            uint4 y = *(const uint4*)(As + a1[i]);
            af[i] = (i32x8){(int)x.x, (int)x.y, (int)x.z, (int)x.w,
                            (int)y.x, (int)y.y, (int)y.z, (int)y.w};
        }
#pragma unroll
        for (int j = 0; j < 4; ++j) {
            uint4 x = *(const uint4*)(Bs + b0[j]);
            uint4 y = *(const uint4*)(Bs + b1[j]);
            bf[j] = (i32x8){(int)x.x, (int)x.y, (int)x.z, (int)x.w,
                            (int)y.x, (int)y.y, (int)y.z, (int)y.w};
        }
#pragma unroll
        for (int i = 0; i < 4; ++i)
#pragma unroll
            for (int j = 0; j < 4; ++j)
                acc[i][j] = __builtin_amdgcn_mfma_scale_f32_16x16x128_f8f6f4(
                    af[i], bf[j], acc[i][j], 0, 0,
                    0, 0x7F7F7F7F, 0, 0x7F7F7F7F);   // unit scales (E8M0 127)
    }

    // epilogue: exp + row-sum. C/D layout: col = lane&15, row = q*4 + reg.
#pragma unroll
    for (int i = 0; i < 4; ++i) {
        float s0 = 0.f, s1 = 0.f, s2 = 0.f, s3 = 0.f;
#pragma unroll
        for (int j = 0; j < 4; ++j) {
            s0 += __expf(fmaf(w, acc[i][j][0] + 1e-6f, bb));
            s1 += __expf(fmaf(w, acc[i][j][1] + 1e-6f, bb));
            s2 += __expf(fmaf(w, acc[i][j][2] + 1e-6f, bb));
            s3 += __expf(fmaf(w, acc[i][j][3] + 1e-6f, bb));
        }
#pragma unroll
        for (int o = 1; o < 16; o <<= 1) {
            s0 += __shfl_xor(s0, o); s1 += __shfl_xor(s1, o);
            s2 += __shfl_xor(s2, o); s3 += __shfl_xor(s3, o);
        }
        if (ml < 4) {
            float sv = (ml == 0) ? s0 : (ml == 1) ? s1 : (ml == 2) ? s2 : s3;
            int grow = tileM * 128 + wm * 64 + i * 16 + q * 4 + ml;
            atomicAdd(&rowsum[grow], sv);
        }
    }
}

// ---------------------------------------------------------------------------
// Finalize (R6-validated): per-row diagonal fixup + log + reduction.
// Separate dispatch = cheap device-wide visibility of rowsum (no fence).
// ---------------------------------------------------------------------------
__global__ __launch_bounds__(256) void finalize(const float* __restrict__ rowsum,
                                                const float* __restrict__ diag,
                                                const float* __restrict__ csd,
                                                const float* __restrict__ wp,
                                                const float* __restrict__ bp,
                                                float* __restrict__ out) {
    __shared__ float s_red[4];
    const int r = blockIdx.x * 256 + threadIdx.x;   // 80*256 == 20480 exactly
    const float w = *wp, bb = *bp;
    const float dg = diag[r];
    const float pos = fmaf(w, dg + 1e-6f, bb);
    const float S = rowsum[r] - __expf(fmaf(w, csd[r] + 1e-6f, bb)) + __expf(pos);
    float term = __logf(S + 1e-6f) - pos;
    const int lane = threadIdx.x & 63, wv = threadIdx.x >> 6;
#pragma unroll
    for (int o = 32; o; o >>= 1) term += __shfl_xor(term, o);
    if (lane == 0) s_red[wv] = term;
    __syncthreads();
    if (threadIdx.x == 0) atomicAdd(out, s_red[0] + s_red[1] + s_red[2] + s_red[3]);
}

extern "C" void kernel_launch(void* const* d_in, const int* in_sizes, int n_in,
                              void* d_out, int out_size, void* d_ws, size_t ws_size,
                              hipStream_t stream) {
    const float* E = (const float*)d_in[0];
    const float* wp = (const float*)d_in[1];
    const float* bp = (const float*)d_in[2];
    float* out = (float*)d_out;

    char* ws = (char*)d_ws;
    u8* A      = (u8*)(ws);                        // 20480*512   = 10,485,760 B
    u8* Bc     = (u8*)(ws + 10485760);             //  1024*512   =     524,288 B
    float* dg  = (float*)(ws + 11010048);          // 20480*4
    float* cs  = (float*)(ws + 11091968);          // 20480*4
    float* rs  = (float*)(ws + 11173888);          // 20480*4

    prep_f<<<NSPK, 256, 0, stream>>>(E, A, Bc, dg, cs, rs, out);
    gemm_mx<<<dim3(160, 8), 256, 0, stream>>>(A, Bc, wp, bp, rs);
    finalize<<<80, 256, 0, stream>>>(rs, dg, cs, wp, bp, out);
}